// Round 5
// baseline (85.629 us; speedup 1.0000x reference)
//
#include <hip/hip_runtime.h>
#include <hip/hip_bf16.h>

// RisingTideAttentionV2: out[m,:] = norm( exp(-||x_m - p_n|| / efft_n) ) @ V
// M=16384, N=4096, D=128. d2 = x2[m] + p2[n] - 2*dot(x_m,p_n). NEURON_SCALE=0.05125
//
// Screen-based structure: w = exp2f(sqrtf(d2)*cg) (cg<0) is EXACTLY 0.0f when
// sqrt(d2)*cg <= -151. We precompute pc[n] = p2[n] - thr2[n] with
// thr = 154*efft*ln2 (z-margin 154 vs true cutoff ~150 absorbs sqrt/mul/fma
// rounding), so the common path is: e = fmaf(s,-2,x2+pc); all e>=0 (wave vote)
// => every weight is exactly 0 => contributes 0 to numerator AND denominator
// => skip. No sqrt/exp2/LDS/barriers/atomics in the common path. The precise
// path (cold) computes the exact original expressions, preserving semantics
// for any input.

typedef __attribute__((ext_vector_type(8))) short short8;
typedef __attribute__((ext_vector_type(4))) float f32x4;

#define MTOT 16384
#define NTOT 4096
#define DD   128

__device__ __forceinline__ short f2bf(float f) {
    unsigned u = __float_as_uint(f);
    unsigned r = (u + 0x7fffu + ((u >> 16) & 1u)) >> 16;
    return (short)r;
}

// ---------------- prep ----------------
// blocks 0..511:    X -> bf16 Xb + x2g (32 rows each)
// blocks 512..639:  pos/val/temp -> Pb, p2g, cg, pcg, Vt (32 n each)
// blocks 640..1151: zero d_out (16 KB each)
// blocks 1152..1155: zero rsum_g
__global__ __launch_bounds__(256) void tide_prep(
    const float* __restrict__ x, const float* __restrict__ pos,
    const float* __restrict__ val, const float* __restrict__ temp,
    short* __restrict__ Xb, float* __restrict__ x2g,
    short* __restrict__ Pb, float* __restrict__ p2g, float* __restrict__ cg,
    float* __restrict__ pcg, short* __restrict__ Vt,
    float* __restrict__ outz, float* __restrict__ rsz)
{
    const int bid = blockIdx.x, tid = threadIdx.x;
    if (bid < 512) {
        const int r = tid >> 3, sub = tid & 7;
        const int row = bid * 32 + r;
        const float* src = x + (size_t)row * DD + sub * 16;
        f32x4 a0 = ((const f32x4*)src)[0];
        f32x4 a1 = ((const f32x4*)src)[1];
        f32x4 a2 = ((const f32x4*)src)[2];
        f32x4 a3 = ((const f32x4*)src)[3];
        short8 h0, h1;
        h0[0]=f2bf(a0[0]); h0[1]=f2bf(a0[1]); h0[2]=f2bf(a0[2]); h0[3]=f2bf(a0[3]);
        h0[4]=f2bf(a1[0]); h0[5]=f2bf(a1[1]); h0[6]=f2bf(a1[2]); h0[7]=f2bf(a1[3]);
        h1[0]=f2bf(a2[0]); h1[1]=f2bf(a2[1]); h1[2]=f2bf(a2[2]); h1[3]=f2bf(a2[3]);
        h1[4]=f2bf(a3[0]); h1[5]=f2bf(a3[1]); h1[6]=f2bf(a3[2]); h1[7]=f2bf(a3[3]);
        *(short8*)(Xb + (size_t)row * DD + sub * 16)     = h0;
        *(short8*)(Xb + (size_t)row * DD + sub * 16 + 8) = h1;
        float s = a0[0]*a0[0]+a0[1]*a0[1]+a0[2]*a0[2]+a0[3]*a0[3]
                + a1[0]*a1[0]+a1[1]*a1[1]+a1[2]*a1[2]+a1[3]*a1[3]
                + a2[0]*a2[0]+a2[1]*a2[1]+a2[2]*a2[2]+a2[3]*a2[3]
                + a3[0]*a3[0]+a3[1]*a3[1]+a3[2]*a3[2]+a3[3]*a3[3];
        s += __shfl_xor(s, 1); s += __shfl_xor(s, 2); s += __shfl_xor(s, 4);
        if (sub == 0) x2g[row] = s;
    } else if (bid < 640) {
        __shared__ short ldsv[32][132];
        const int r = tid >> 3, sub = tid & 7;
        const int n0 = (bid - 512) * 32;
        const int n = n0 + r;
        const float* ps = pos + (size_t)n * DD + sub * 16;
        f32x4 a0 = ((const f32x4*)ps)[0];
        f32x4 a1 = ((const f32x4*)ps)[1];
        f32x4 a2 = ((const f32x4*)ps)[2];
        f32x4 a3 = ((const f32x4*)ps)[3];
        short8 h0, h1;
        h0[0]=f2bf(a0[0]); h0[1]=f2bf(a0[1]); h0[2]=f2bf(a0[2]); h0[3]=f2bf(a0[3]);
        h0[4]=f2bf(a1[0]); h0[5]=f2bf(a1[1]); h0[6]=f2bf(a1[2]); h0[7]=f2bf(a1[3]);
        h1[0]=f2bf(a2[0]); h1[1]=f2bf(a2[1]); h1[2]=f2bf(a2[2]); h1[3]=f2bf(a2[3]);
        h1[4]=f2bf(a3[0]); h1[5]=f2bf(a3[1]); h1[6]=f2bf(a3[2]); h1[7]=f2bf(a3[3]);
        *(short8*)(Pb + (size_t)n * DD + sub * 16)     = h0;
        *(short8*)(Pb + (size_t)n * DD + sub * 16 + 8) = h1;
        float s = a0[0]*a0[0]+a0[1]*a0[1]+a0[2]*a0[2]+a0[3]*a0[3]
                + a1[0]*a1[0]+a1[1]*a1[1]+a1[2]*a1[2]+a1[3]*a1[3]
                + a2[0]*a2[0]+a2[1]*a2[1]+a2[2]*a2[2]+a2[3]*a2[3]
                + a3[0]*a3[0]+a3[1]*a3[1]+a3[2]*a3[2]+a3[3]*a3[3];
        s += __shfl_xor(s, 1); s += __shfl_xor(s, 2); s += __shfl_xor(s, 4);
        if (sub == 0) {
            p2g[n] = s;
            float efft = (fabsf(temp[n]) + 0.1f) * 0.05125f;
            cg[n] = -1.4426950408889634f / efft;  // exp(-d/efft)=exp2(d*cg)
            float thr = 154.0f * efft * 0.6931471805599453f;  // margin: z0=154
            pcg[n] = s - thr * thr;               // p2 - thr2
        }
        const float* vs = val + (size_t)n * DD + sub * 16;
        f32x4 b0 = ((const f32x4*)vs)[0];
        f32x4 b1 = ((const f32x4*)vs)[1];
        f32x4 b2 = ((const f32x4*)vs)[2];
        f32x4 b3 = ((const f32x4*)vs)[3];
        short* dstv = &ldsv[r][sub * 16];
        dstv[0]=f2bf(b0[0]); dstv[1]=f2bf(b0[1]); dstv[2]=f2bf(b0[2]); dstv[3]=f2bf(b0[3]);
        dstv[4]=f2bf(b1[0]); dstv[5]=f2bf(b1[1]); dstv[6]=f2bf(b1[2]); dstv[7]=f2bf(b1[3]);
        dstv[8]=f2bf(b2[0]); dstv[9]=f2bf(b2[1]); dstv[10]=f2bf(b2[2]); dstv[11]=f2bf(b2[3]);
        dstv[12]=f2bf(b3[0]); dstv[13]=f2bf(b3[1]); dstv[14]=f2bf(b3[2]); dstv[15]=f2bf(b3[3]);
        __syncthreads();
        const int d = tid >> 1, half = tid & 1;
        short8 t0, t1;
        #pragma unroll
        for (int j = 0; j < 8; ++j) t0[j] = ldsv[half * 16 + j][d];
        #pragma unroll
        for (int j = 0; j < 8; ++j) t1[j] = ldsv[half * 16 + 8 + j][d];
        *(short8*)(Vt + (size_t)d * NTOT + n0 + half * 16)     = t0;
        *(short8*)(Vt + (size_t)d * NTOT + n0 + half * 16 + 8) = t1;
    } else if (bid < 1152) {
        f32x4 z = {0.f, 0.f, 0.f, 0.f};
        float* dst = outz + (size_t)(bid - 640) * 4096;
        #pragma unroll
        for (int j = 0; j < 4; ++j)
            *(f32x4*)(dst + (size_t)(tid + 256 * j) * 4) = z;
    } else {
        f32x4 z = {0.f, 0.f, 0.f, 0.f};
        float* dst = rsz + (size_t)(bid - 1152) * 4096;
        #pragma unroll
        for (int j = 0; j < 4; ++j)
            *(f32x4*)(dst + (size_t)(tid + 256 * j) * 4) = z;
    }
}

// ---------------- main ----------------
// grid = 2048: blockIdx = mc*32 + nb. Block: rows mc*256..+255, cols nb*128..+127.
// Wave w: cols nb*128 + w*32 .. +31. 16 iters of 16 rows, unrolled 2x ping-pong.
__global__ __launch_bounds__(256, 4) void tide_main(
    const short* __restrict__ Xb, const float* __restrict__ x2g,
    const short* __restrict__ Pb, const float* __restrict__ p2g,
    const float* __restrict__ cg, const float* __restrict__ pcg,
    const short* __restrict__ Vt,
    float* __restrict__ rsum_g, float* __restrict__ oaccum)
{
    __shared__ __attribute__((aligned(16))) short lds_w[4][16 * 32];  // cold path only

    const int tid = threadIdx.x;
    const int wid = tid >> 6, lane = tid & 63;
    const int lo = lane & 15, hi = lane >> 4;
    const int nb = blockIdx.x & 31, mc = blockIdx.x >> 5;
    const int mb = mc * 256;
    const int ns0 = nb * 128 + wid * 32;

    // loop-invariant P fragments: lane holds P[n=base+lo][k=(kf*4+hi)*8+j]
    short8 pf0[4], pf1[4];
    #pragma unroll
    for (int kf = 0; kf < 4; ++kf) {
        pf0[kf] = *(const short8*)(Pb + (size_t)(ns0 + lo) * DD + (kf * 4 + hi) * 8);
        pf1[kf] = *(const short8*)(Pb + (size_t)(ns0 + 16 + lo) * DD + (kf * 4 + hi) * 8);
    }
    const float pc0 = pcg[ns0 + lo], pc1 = pcg[ns0 + 16 + lo];

    const short* xrow = Xb + (size_t)(mb + lo) * DD;   // this lane's row base

    // cold exact path (weights possibly nonzero): recompute precisely, PV, atomics
    auto rare = [&](const f32x4& s0, const f32x4& s1, const f32x4& x2u, int m0) {
        const float p2v0 = p2g[ns0 + lo], p2v1 = p2g[ns0 + 16 + lo];
        const float cv0  = cg[ns0 + lo],  cv1  = cg[ns0 + 16 + lo];
        float w[8], wmax = 0.f;
        #pragma unroll
        for (int r = 0; r < 4; ++r) {
            float d2a = fmaf(s0[r], -2.f, x2u[r] + p2v0);
            float d2b = fmaf(s1[r], -2.f, x2u[r] + p2v1);
            d2a = fmaxf(d2a, 0.f); d2b = fmaxf(d2b, 0.f);
            float wa = exp2f(__builtin_amdgcn_sqrtf(d2a) * cv0);
            float wb = exp2f(__builtin_amdgcn_sqrtf(d2b) * cv1);
            w[r] = wa; w[4 + r] = wb;
            wmax = fmaxf(wmax, fmaxf(wa, wb));
        }
        if (__any(wmax > 0.f)) {
            #pragma unroll
            for (int r = 0; r < 4; ++r) {
                float v = w[r] + w[4 + r];
                v += __shfl_xor(v, 1); v += __shfl_xor(v, 2);
                v += __shfl_xor(v, 4); v += __shfl_xor(v, 8);
                if (lo == 0) atomicAdd(&rsum_g[m0 + hi * 4 + r], v);
            }
            #pragma unroll
            for (int r = 0; r < 4; ++r) {
                lds_w[wid][(hi * 4 + r) * 32 + lo]      = f2bf(w[r]);
                lds_w[wid][(hi * 4 + r) * 32 + 16 + lo] = f2bf(w[4 + r]);
            }
            short8 wfr = *(const short8*)(&lds_w[wid][lo * 32 + hi * 8]);
            #pragma unroll
            for (int df = 0; df < 8; ++df) {
                short8 vf = *(const short8*)(Vt + (size_t)(df * 16 + lo) * NTOT + ns0 + hi * 8);
                f32x4 of = {0.f,0.f,0.f,0.f};
                of = __builtin_amdgcn_mfma_f32_16x16x32_bf16(wfr, vf, of, 0, 0, 0);
                #pragma unroll
                for (int r = 0; r < 4; ++r)
                    atomicAdd(&oaccum[(size_t)(m0 + hi * 4 + r) * DD + df * 16 + lo], of[r]);
            }
        }
    };

    short8 xfA[4], xfB[4];
    f32x4 x2A, x2B;
    #pragma unroll
    for (int kf = 0; kf < 4; ++kf)
        xfA[kf] = *(const short8*)(xrow + (kf * 4 + hi) * 8);
    x2A = *(const f32x4*)(x2g + mb + hi * 4);

// body for iter T: uses (XF, X2U), prefetches T+1 into (XN, X2N).
// T=15's prefetch reads 4 KB past this mc-chunk -- still inside d_ws, unused.
#define TIDE_BODY(T, XF, X2U, XN, X2N)                                         \
    {                                                                          \
        const int m0 = mb + (T) * 16;                                          \
        const short* xnext = xrow + (size_t)((T) + 1) * 16 * DD;               \
        _Pragma("unroll")                                                      \
        for (int kf = 0; kf < 4; ++kf)                                         \
            XN[kf] = *(const short8*)(xnext + (kf * 4 + hi) * 8);              \
        X2N = *(const f32x4*)(x2g + m0 + 16 + hi * 4);                         \
        f32x4 s0 = {0.f,0.f,0.f,0.f}, s1 = {0.f,0.f,0.f,0.f};                  \
        _Pragma("unroll")                                                      \
        for (int kf = 0; kf < 4; ++kf) {                                       \
            s0 = __builtin_amdgcn_mfma_f32_16x16x32_bf16(XF[kf], pf0[kf], s0, 0, 0, 0); \
            s1 = __builtin_amdgcn_mfma_f32_16x16x32_bf16(XF[kf], pf1[kf], s1, 0, 0, 0); \
        }                                                                      \
        float ea0 = fmaf(s0[0], -2.f, X2U[0] + pc0);                           \
        float ea1 = fmaf(s0[1], -2.f, X2U[1] + pc0);                           \
        float ea2 = fmaf(s0[2], -2.f, X2U[2] + pc0);                           \
        float ea3 = fmaf(s0[3], -2.f, X2U[3] + pc0);                           \
        float eb0 = fmaf(s1[0], -2.f, X2U[0] + pc1);                           \
        float eb1 = fmaf(s1[1], -2.f, X2U[1] + pc1);                           \
        float eb2 = fmaf(s1[2], -2.f, X2U[2] + pc1);                           \
        float eb3 = fmaf(s1[3], -2.f, X2U[3] + pc1);                           \
        float emin = fminf(fminf(fminf(ea0, ea1), fminf(ea2, ea3)),            \
                           fminf(fminf(eb0, eb1), fminf(eb2, eb3)));           \
        if (__builtin_expect(__any(!(emin >= 0.f)), 0))                        \
            rare(s0, s1, X2U, m0);                                             \
    }

    #pragma unroll 1
    for (int t = 0; t < 16; t += 2) {
        TIDE_BODY(t,     xfA, x2A, xfB, x2B)
        TIDE_BODY(t + 1, xfB, x2B, xfA, x2A)
    }
#undef TIDE_BODY
}

// ---------------- normalize: only rows with nonzero rsum need work ----------
__global__ __launch_bounds__(256) void tide_norm(
    const float* __restrict__ rsum_g, float* __restrict__ outp)
{
    const int row = blockIdx.x * 256 + threadIdx.x;
    float s = rsum_g[row];
    if (s != 0.f) {
        float inv = 1.f / (s + 1e-8f);
        float* p = outp + (size_t)row * DD;
        #pragma unroll 4
        for (int j = 0; j < DD / 4; ++j) {
            f32x4 v = *(f32x4*)(p + j * 4);
            v[0] *= inv; v[1] *= inv; v[2] *= inv; v[3] *= inv;
            *(f32x4*)(p + j * 4) = v;
        }
    }
    // s == 0: out row already exact (0 / (0 + 1e-8) = 0, pre-zeroed)
}

extern "C" void kernel_launch(void* const* d_in, const int* in_sizes, int n_in,
                              void* d_out, int out_size, void* d_ws, size_t ws_size,
                              hipStream_t stream) {
    const float* x    = (const float*)d_in[0];  // [8,2048,128]
    const float* pos  = (const float*)d_in[1];  // [4096,128]
    const float* val  = (const float*)d_in[2];  // [4096,128]
    const float* temp = (const float*)d_in[3];  // [4096]
    float* out = (float*)d_out;

    char* ws = (char*)d_ws;
    short* Xb     = (short*)(ws);                    // 4 MB
    short* Pb     = (short*)(ws + 4194304);          // 1 MB
    short* Vt     = (short*)(ws + 5242880);          // 1 MB
    float* x2g    = (float*)(ws + 6291456);          // 64 KB
    float* p2g    = (float*)(ws + 6356992);          // 16 KB
    float* cg     = (float*)(ws + 6373376);          // 16 KB
    float* pcg    = (float*)(ws + 6389760);          // 16 KB
    float* rsum_g = (float*)(ws + 6406144);          // 64 KB

    hipLaunchKernelGGL(tide_prep, dim3(1156), dim3(256), 0, stream,
                       x, pos, val, temp, Xb, x2g, Pb, p2g, cg, pcg, Vt, out, rsum_g);
    hipLaunchKernelGGL(tide_main, dim3(2048), dim3(256), 0, stream,
                       Xb, x2g, Pb, p2g, cg, pcg, Vt, rsum_g, out);
    hipLaunchKernelGGL(tide_norm, dim3(64), dim3(256), 0, stream,
                       rsum_g, out);
}

// Round 6
// 53.319 us; speedup vs baseline: 1.6060x; 1.6060x over previous
//
#include <hip/hip_runtime.h>
#include <hip/hip_bf16.h>

// RisingTideAttentionV2: out[m,:] = norm( exp(-||x_m - p_n|| / efft_n) ) @ V
// M=16384, N=4096, D=128. d2 = x2[m] + p2[n] - 2*dot(x_m,p_n). NEURON_SCALE=0.05125
//
// Screen: w = exp2f(sqrtf(d2)*cg) (cg<0) is EXACTLY 0.0f when sqrt(d2)*cg <=
// -151. pc[n] = p2[n] - thr2[n], thr = 154*efft*ln2 (margin absorbs rounding).
// e = fmaf(s,-2,x2+pc) >= 0 for ALL elements => every weight is exactly 0 =>
// tile contributes 0 to numerator AND denominator => skip. The hot loop is
// BRANCHLESS: it only accumulates emin (min) and echk (sum; catches NaNs that
// IEEE fminf would swallow). One vote per wave at the end; cold path redoes
// the whole wave's tile with the exact original math (any-input correct).

typedef __attribute__((ext_vector_type(8))) short short8;
typedef __attribute__((ext_vector_type(4))) float f32x4;

#define MTOT 16384
#define NTOT 4096
#define DD   128

__device__ __forceinline__ short f2bf(float f) {
    unsigned u = __float_as_uint(f);
    unsigned r = (u + 0x7fffu + ((u >> 16) & 1u)) >> 16;
    return (short)r;
}

// ---------------- prep ----------------
// blocks 0..511:    X -> bf16 Xb + x2g (32 rows each)
// blocks 512..639:  pos/val/temp -> Pb, p2g, cg, pcg, Vt (32 n each)
// blocks 640..1151: zero d_out (16 KB each)
// blocks 1152..1155: zero rsum_g
__global__ __launch_bounds__(256) void tide_prep(
    const float* __restrict__ x, const float* __restrict__ pos,
    const float* __restrict__ val, const float* __restrict__ temp,
    short* __restrict__ Xb, float* __restrict__ x2g,
    short* __restrict__ Pb, float* __restrict__ p2g, float* __restrict__ cg,
    float* __restrict__ pcg, short* __restrict__ Vt,
    float* __restrict__ outz, float* __restrict__ rsz)
{
    const int bid = blockIdx.x, tid = threadIdx.x;
    if (bid < 512) {
        const int r = tid >> 3, sub = tid & 7;
        const int row = bid * 32 + r;
        const float* src = x + (size_t)row * DD + sub * 16;
        f32x4 a0 = ((const f32x4*)src)[0];
        f32x4 a1 = ((const f32x4*)src)[1];
        f32x4 a2 = ((const f32x4*)src)[2];
        f32x4 a3 = ((const f32x4*)src)[3];
        short8 h0, h1;
        h0[0]=f2bf(a0[0]); h0[1]=f2bf(a0[1]); h0[2]=f2bf(a0[2]); h0[3]=f2bf(a0[3]);
        h0[4]=f2bf(a1[0]); h0[5]=f2bf(a1[1]); h0[6]=f2bf(a1[2]); h0[7]=f2bf(a1[3]);
        h1[0]=f2bf(a2[0]); h1[1]=f2bf(a2[1]); h1[2]=f2bf(a2[2]); h1[3]=f2bf(a2[3]);
        h1[4]=f2bf(a3[0]); h1[5]=f2bf(a3[1]); h1[6]=f2bf(a3[2]); h1[7]=f2bf(a3[3]);
        *(short8*)(Xb + (size_t)row * DD + sub * 16)     = h0;
        *(short8*)(Xb + (size_t)row * DD + sub * 16 + 8) = h1;
        float s = a0[0]*a0[0]+a0[1]*a0[1]+a0[2]*a0[2]+a0[3]*a0[3]
                + a1[0]*a1[0]+a1[1]*a1[1]+a1[2]*a1[2]+a1[3]*a1[3]
                + a2[0]*a2[0]+a2[1]*a2[1]+a2[2]*a2[2]+a2[3]*a2[3]
                + a3[0]*a3[0]+a3[1]*a3[1]+a3[2]*a3[2]+a3[3]*a3[3];
        s += __shfl_xor(s, 1); s += __shfl_xor(s, 2); s += __shfl_xor(s, 4);
        if (sub == 0) x2g[row] = s;
    } else if (bid < 640) {
        __shared__ short ldsv[32][132];
        const int r = tid >> 3, sub = tid & 7;
        const int n0 = (bid - 512) * 32;
        const int n = n0 + r;
        const float* ps = pos + (size_t)n * DD + sub * 16;
        f32x4 a0 = ((const f32x4*)ps)[0];
        f32x4 a1 = ((const f32x4*)ps)[1];
        f32x4 a2 = ((const f32x4*)ps)[2];
        f32x4 a3 = ((const f32x4*)ps)[3];
        short8 h0, h1;
        h0[0]=f2bf(a0[0]); h0[1]=f2bf(a0[1]); h0[2]=f2bf(a0[2]); h0[3]=f2bf(a0[3]);
        h0[4]=f2bf(a1[0]); h0[5]=f2bf(a1[1]); h0[6]=f2bf(a1[2]); h0[7]=f2bf(a1[3]);
        h1[0]=f2bf(a2[0]); h1[1]=f2bf(a2[1]); h1[2]=f2bf(a2[2]); h1[3]=f2bf(a2[3]);
        h1[4]=f2bf(a3[0]); h1[5]=f2bf(a3[1]); h1[6]=f2bf(a3[2]); h1[7]=f2bf(a3[3]);
        *(short8*)(Pb + (size_t)n * DD + sub * 16)     = h0;
        *(short8*)(Pb + (size_t)n * DD + sub * 16 + 8) = h1;
        float s = a0[0]*a0[0]+a0[1]*a0[1]+a0[2]*a0[2]+a0[3]*a0[3]
                + a1[0]*a1[0]+a1[1]*a1[1]+a1[2]*a1[2]+a1[3]*a1[3]
                + a2[0]*a2[0]+a2[1]*a2[1]+a2[2]*a2[2]+a2[3]*a2[3]
                + a3[0]*a3[0]+a3[1]*a3[1]+a3[2]*a3[2]+a3[3]*a3[3];
        s += __shfl_xor(s, 1); s += __shfl_xor(s, 2); s += __shfl_xor(s, 4);
        if (sub == 0) {
            p2g[n] = s;
            float efft = (fabsf(temp[n]) + 0.1f) * 0.05125f;
            cg[n] = -1.4426950408889634f / efft;  // exp(-d/efft)=exp2(d*cg)
            float thr = 154.0f * efft * 0.6931471805599453f;  // margin: z0=154
            pcg[n] = s - thr * thr;               // p2 - thr2
        }
        const float* vs = val + (size_t)n * DD + sub * 16;
        f32x4 b0 = ((const f32x4*)vs)[0];
        f32x4 b1 = ((const f32x4*)vs)[1];
        f32x4 b2 = ((const f32x4*)vs)[2];
        f32x4 b3 = ((const f32x4*)vs)[3];
        short* dstv = &ldsv[r][sub * 16];
        dstv[0]=f2bf(b0[0]); dstv[1]=f2bf(b0[1]); dstv[2]=f2bf(b0[2]); dstv[3]=f2bf(b0[3]);
        dstv[4]=f2bf(b1[0]); dstv[5]=f2bf(b1[1]); dstv[6]=f2bf(b1[2]); dstv[7]=f2bf(b1[3]);
        dstv[8]=f2bf(b2[0]); dstv[9]=f2bf(b2[1]); dstv[10]=f2bf(b2[2]); dstv[11]=f2bf(b2[3]);
        dstv[12]=f2bf(b3[0]); dstv[13]=f2bf(b3[1]); dstv[14]=f2bf(b3[2]); dstv[15]=f2bf(b3[3]);
        __syncthreads();
        const int d = tid >> 1, half = tid & 1;
        short8 t0, t1;
        #pragma unroll
        for (int j = 0; j < 8; ++j) t0[j] = ldsv[half * 16 + j][d];
        #pragma unroll
        for (int j = 0; j < 8; ++j) t1[j] = ldsv[half * 16 + 8 + j][d];
        *(short8*)(Vt + (size_t)d * NTOT + n0 + half * 16)     = t0;
        *(short8*)(Vt + (size_t)d * NTOT + n0 + half * 16 + 8) = t1;
    } else if (bid < 1152) {
        f32x4 z = {0.f, 0.f, 0.f, 0.f};
        float* dst = outz + (size_t)(bid - 640) * 4096;
        #pragma unroll
        for (int j = 0; j < 4; ++j)
            *(f32x4*)(dst + (size_t)(tid + 256 * j) * 4) = z;
    } else {
        f32x4 z = {0.f, 0.f, 0.f, 0.f};
        float* dst = rsz + (size_t)(bid - 1152) * 4096;
        #pragma unroll
        for (int j = 0; j < 4; ++j)
            *(f32x4*)(dst + (size_t)(tid + 256 * j) * 4) = z;
    }
}

// ---------------- main: branchless straight-line hot path ----------------
// grid = 1024 (= 4 blocks/CU, all resident): blockIdx = mc*16 + nb.
// Block: rows mc*256..+255, cols nb*256..+255. Wave w: 64 cols at nb*256+w*64.
// Hot loop: 16 fully-unrolled iterations (16 rows each), no branches/stores.
__global__ __launch_bounds__(256, 4) void tide_main(
    const short* __restrict__ Xb, const float* __restrict__ x2g,
    const short* __restrict__ Pb, const float* __restrict__ p2g,
    const float* __restrict__ cg, const float* __restrict__ pcg,
    const short* __restrict__ Vt,
    float* __restrict__ rsum_g, float* __restrict__ oaccum)
{
    __shared__ __attribute__((aligned(16))) short lds_w[4][16 * 32];  // cold only

    const int tid = threadIdx.x;
    const int wid = tid >> 6, lane = tid & 63;
    const int lo = lane & 15, hi = lane >> 4;
    const int nb = blockIdx.x & 15, mc = blockIdx.x >> 4;
    const int mb = mc * 256;
    const int c0 = nb * 256 + wid * 64;   // wave's first col (owns 64)

    // loop-invariant P fragments: lane holds P[n=c0+f*16+lo][k=(kf*4+hi)*8+j]
    short8 pf[4][4];
    float pc[4];
    #pragma unroll
    for (int f = 0; f < 4; ++f) {
        #pragma unroll
        for (int kf = 0; kf < 4; ++kf)
            pf[f][kf] = *(const short8*)(Pb + (size_t)(c0 + f * 16 + lo) * DD
                                            + (kf * 4 + hi) * 8);
        pc[f] = pcg[c0 + f * 16 + lo];
    }

    const short* xrow = Xb + (size_t)(mb + lo) * DD;

    float emin = 3.4e38f;   // min of all e (fminf drops NaNs...)
    float echk = 0.f;       // ...so a sum companion catches them

    #pragma unroll
    for (int t = 0; t < 16; ++t) {
        short8 xf[4];
        #pragma unroll
        for (int kf = 0; kf < 4; ++kf)
            xf[kf] = *(const short8*)(xrow + (size_t)t * 16 * DD + (kf * 4 + hi) * 8);
        f32x4 x2r = *(const f32x4*)(x2g + mb + t * 16 + hi * 4);
        #pragma unroll
        for (int f = 0; f < 4; ++f) {
            f32x4 s = {0.f, 0.f, 0.f, 0.f};
            #pragma unroll
            for (int kf = 0; kf < 4; ++kf)
                s = __builtin_amdgcn_mfma_f32_16x16x32_bf16(xf[kf], pf[f][kf], s, 0, 0, 0);
            #pragma unroll
            for (int r = 0; r < 4; ++r) {
                float e = fmaf(s[r], -2.f, x2r[r] + pc[f]);
                emin = fminf(emin, e);
                echk += e;
            }
        }
    }

    const int bad = (!(emin >= 0.f)) | (echk != echk);
    if (__builtin_expect(__any(bad), 0)) {
        // ---- cold exact path: redo this wave's whole tile precisely ----
        float p2v[4], cv[4];
        #pragma unroll
        for (int f = 0; f < 4; ++f) {
            p2v[f] = p2g[c0 + f * 16 + lo];
            cv[f]  = cg [c0 + f * 16 + lo];
        }
        #pragma unroll 1
        for (int t = 0; t < 16; ++t) {
            const int m0 = mb + t * 16;
            short8 xf[4];
            #pragma unroll
            for (int kf = 0; kf < 4; ++kf)
                xf[kf] = *(const short8*)(xrow + (size_t)t * 16 * DD + (kf * 4 + hi) * 8);
            f32x4 x2r = *(const f32x4*)(x2g + m0 + hi * 4);
            #pragma unroll
            for (int pr = 0; pr < 2; ++pr) {      // pairs of 16-col frags
                f32x4 s0 = {0.f,0.f,0.f,0.f}, s1 = {0.f,0.f,0.f,0.f};
                #pragma unroll
                for (int kf = 0; kf < 4; ++kf) {
                    s0 = __builtin_amdgcn_mfma_f32_16x16x32_bf16(xf[kf], pf[2*pr][kf],   s0, 0, 0, 0);
                    s1 = __builtin_amdgcn_mfma_f32_16x16x32_bf16(xf[kf], pf[2*pr+1][kf], s1, 0, 0, 0);
                }
                float w[8], wmax = 0.f;
                #pragma unroll
                for (int r = 0; r < 4; ++r) {
                    float d2a = fmaf(s0[r], -2.f, x2r[r] + p2v[2*pr]);
                    float d2b = fmaf(s1[r], -2.f, x2r[r] + p2v[2*pr+1]);
                    d2a = fmaxf(d2a, 0.f); d2b = fmaxf(d2b, 0.f);
                    float wa = exp2f(__builtin_amdgcn_sqrtf(d2a) * cv[2*pr]);
                    float wb = exp2f(__builtin_amdgcn_sqrtf(d2b) * cv[2*pr+1]);
                    w[r] = wa; w[4 + r] = wb;
                    wmax = fmaxf(wmax, fmaxf(wa, wb));
                }
                if (__any(wmax > 0.f)) {
                    #pragma unroll
                    for (int r = 0; r < 4; ++r) {
                        float v = w[r] + w[4 + r];
                        v += __shfl_xor(v, 1); v += __shfl_xor(v, 2);
                        v += __shfl_xor(v, 4); v += __shfl_xor(v, 8);
                        if (lo == 0) atomicAdd(&rsum_g[m0 + hi * 4 + r], v);
                    }
                    #pragma unroll
                    for (int r = 0; r < 4; ++r) {
                        lds_w[wid][(hi * 4 + r) * 32 + lo]      = f2bf(w[r]);
                        lds_w[wid][(hi * 4 + r) * 32 + 16 + lo] = f2bf(w[4 + r]);
                    }
                    short8 wfr = *(const short8*)(&lds_w[wid][lo * 32 + hi * 8]);
                    #pragma unroll
                    for (int df = 0; df < 8; ++df) {
                        short8 vf = *(const short8*)(Vt + (size_t)(df * 16 + lo) * NTOT
                                                        + c0 + pr * 32 + hi * 8);
                        f32x4 of = {0.f,0.f,0.f,0.f};
                        of = __builtin_amdgcn_mfma_f32_16x16x32_bf16(wfr, vf, of, 0, 0, 0);
                        #pragma unroll
                        for (int r = 0; r < 4; ++r)
                            atomicAdd(&oaccum[(size_t)(m0 + hi * 4 + r) * DD + df * 16 + lo],
                                      of[r]);
                    }
                }
            }
        }
    }
}

// ---------------- normalize: only rows with nonzero rsum need work ----------
__global__ __launch_bounds__(256) void tide_norm(
    const float* __restrict__ rsum_g, float* __restrict__ outp)
{
    const int row = blockIdx.x * 256 + threadIdx.x;
    float s = rsum_g[row];
    if (s != 0.f) {
        float inv = 1.f / (s + 1e-8f);
        float* p = outp + (size_t)row * DD;
        #pragma unroll 4
        for (int j = 0; j < DD / 4; ++j) {
            f32x4 v = *(f32x4*)(p + j * 4);
            v[0] *= inv; v[1] *= inv; v[2] *= inv; v[3] *= inv;
            *(f32x4*)(p + j * 4) = v;
        }
    }
    // s == 0: out row already exact (0 / (0 + 1e-8) = 0, pre-zeroed)
}

extern "C" void kernel_launch(void* const* d_in, const int* in_sizes, int n_in,
                              void* d_out, int out_size, void* d_ws, size_t ws_size,
                              hipStream_t stream) {
    const float* x    = (const float*)d_in[0];  // [8,2048,128]
    const float* pos  = (const float*)d_in[1];  // [4096,128]
    const float* val  = (const float*)d_in[2];  // [4096,128]
    const float* temp = (const float*)d_in[3];  // [4096]
    float* out = (float*)d_out;

    char* ws = (char*)d_ws;
    short* Xb     = (short*)(ws);                    // 4 MB
    short* Pb     = (short*)(ws + 4194304);          // 1 MB
    short* Vt     = (short*)(ws + 5242880);          // 1 MB
    float* x2g    = (float*)(ws + 6291456);          // 64 KB
    float* p2g    = (float*)(ws + 6356992);          // 16 KB
    float* cg     = (float*)(ws + 6373376);          // 16 KB
    float* pcg    = (float*)(ws + 6389760);          // 16 KB
    float* rsum_g = (float*)(ws + 6406144);          // 64 KB

    hipLaunchKernelGGL(tide_prep, dim3(1156), dim3(256), 0, stream,
                       x, pos, val, temp, Xb, x2g, Pb, p2g, cg, pcg, Vt, out, rsum_g);
    hipLaunchKernelGGL(tide_main, dim3(1024), dim3(256), 0, stream,
                       Xb, x2g, Pb, p2g, cg, pcg, Vt, rsum_g, out);
    hipLaunchKernelGGL(tide_norm, dim3(64), dim3(256), 0, stream,
                       rsum_g, out);
}

// Round 7
// 33.696 us; speedup vs baseline: 2.5412x; 1.5823x over previous
//
#include <hip/hip_runtime.h>
#include <hip/hip_bf16.h>

// RisingTideAttentionV2: out[m,:] = norm( exp(-||x_m - p_n|| / efft_n) ) @ V
// M=16384, N=4096, D=128. d2 = x2[m] + p2[n] - 2*dot(x_m,p_n). NEURON_SCALE=0.05125
//
// Screen: w = exp2f(sqrtf(d2)*cg) (cg<0) is EXACTLY 0.0f when sqrt(d2)*cg <=
// -151. pc[n] = p2[n] - thr2[n], thr = 154*efft*ln2 (margin absorbs rounding;
// screen and cold path share the same MFMA s, so the only divergence is fp32
// fma rounding, ~1e-5, vs slack ~0.14). All-e>=0 (one wave vote at the end)
// => every weight is exactly 0 => tile contributes 0 to numerator AND
// denominator => skip. Hot loop is BRANCHLESS and all its memory traffic is
// VGPR-free: X streams via global_load_lds (deep vmcnt queue, counted
// vmcnt(4), double-buffered 16 KB tiles shared by all 4 waves), consumed with
// conflict-free swizzled ds_read_b128. Cold path redoes everything exactly.

typedef __attribute__((ext_vector_type(8))) short short8;
typedef __attribute__((ext_vector_type(4))) float f32x4;

#define MTOT 16384
#define NTOT 4096
#define DD   128

__device__ __forceinline__ short f2bf(float f) {
    unsigned u = __float_as_uint(f);
    unsigned r = (u + 0x7fffu + ((u >> 16) & 1u)) >> 16;
    return (short)r;
}

// ---------------- prep ----------------
// blocks 0..1023:    X -> bf16 Xb + x2g (16 rows each)
// blocks 1024..1279: pos/val/temp -> Pb, p2g, cg, pcg, Vt (16 n each)
// blocks 1280..1791: zero d_out (16 KB each)
// blocks 1792..1795: zero rsum_g
__global__ __launch_bounds__(256) void tide_prep(
    const float* __restrict__ x, const float* __restrict__ pos,
    const float* __restrict__ val, const float* __restrict__ temp,
    short* __restrict__ Xb, float* __restrict__ x2g,
    short* __restrict__ Pb, float* __restrict__ p2g, float* __restrict__ cg,
    float* __restrict__ pcg, short* __restrict__ Vt,
    float* __restrict__ outz, float* __restrict__ rsz)
{
    const int bid = blockIdx.x, tid = threadIdx.x;
    if (bid < 1024) {
        const int r = tid >> 4, sub = tid & 15;
        const int row = bid * 16 + r;
        const float* src = x + (size_t)row * DD + sub * 8;
        f32x4 a0 = ((const f32x4*)src)[0];
        f32x4 a1 = ((const f32x4*)src)[1];
        short8 h;
        h[0]=f2bf(a0[0]); h[1]=f2bf(a0[1]); h[2]=f2bf(a0[2]); h[3]=f2bf(a0[3]);
        h[4]=f2bf(a1[0]); h[5]=f2bf(a1[1]); h[6]=f2bf(a1[2]); h[7]=f2bf(a1[3]);
        *(short8*)(Xb + (size_t)row * DD + sub * 8) = h;
        float s = a0[0]*a0[0]+a0[1]*a0[1]+a0[2]*a0[2]+a0[3]*a0[3]
                + a1[0]*a1[0]+a1[1]*a1[1]+a1[2]*a1[2]+a1[3]*a1[3];
        s += __shfl_xor(s, 1); s += __shfl_xor(s, 2);
        s += __shfl_xor(s, 4); s += __shfl_xor(s, 8);
        if (sub == 0) x2g[row] = s;
    } else if (bid < 1280) {
        __shared__ short ldsv[16][132];
        const int r = tid >> 4, sub = tid & 15;
        const int n0 = (bid - 1024) * 16;
        const int n = n0 + r;
        const float* ps = pos + (size_t)n * DD + sub * 8;
        f32x4 a0 = ((const f32x4*)ps)[0];
        f32x4 a1 = ((const f32x4*)ps)[1];
        short8 h;
        h[0]=f2bf(a0[0]); h[1]=f2bf(a0[1]); h[2]=f2bf(a0[2]); h[3]=f2bf(a0[3]);
        h[4]=f2bf(a1[0]); h[5]=f2bf(a1[1]); h[6]=f2bf(a1[2]); h[7]=f2bf(a1[3]);
        *(short8*)(Pb + (size_t)n * DD + sub * 8) = h;
        float s = a0[0]*a0[0]+a0[1]*a0[1]+a0[2]*a0[2]+a0[3]*a0[3]
                + a1[0]*a1[0]+a1[1]*a1[1]+a1[2]*a1[2]+a1[3]*a1[3];
        s += __shfl_xor(s, 1); s += __shfl_xor(s, 2);
        s += __shfl_xor(s, 4); s += __shfl_xor(s, 8);
        if (sub == 0) {
            p2g[n] = s;
            float efft = (fabsf(temp[n]) + 0.1f) * 0.05125f;
            cg[n] = -1.4426950408889634f / efft;  // exp(-d/efft)=exp2(d*cg)
            float thr = 154.0f * efft * 0.6931471805599453f;
            pcg[n] = s - thr * thr;               // p2 - thr2
        }
        const float* vs = val + (size_t)n * DD + sub * 8;
        f32x4 b0 = ((const f32x4*)vs)[0];
        f32x4 b1 = ((const f32x4*)vs)[1];
        short* dstv = &ldsv[r][sub * 8];
        dstv[0]=f2bf(b0[0]); dstv[1]=f2bf(b0[1]); dstv[2]=f2bf(b0[2]); dstv[3]=f2bf(b0[3]);
        dstv[4]=f2bf(b1[0]); dstv[5]=f2bf(b1[1]); dstv[6]=f2bf(b1[2]); dstv[7]=f2bf(b1[3]);
        __syncthreads();
        const int d = tid >> 1, half = tid & 1;
        short8 t0;
        #pragma unroll
        for (int j = 0; j < 8; ++j) t0[j] = ldsv[half * 8 + j][d];
        *(short8*)(Vt + (size_t)d * NTOT + n0 + half * 8) = t0;
    } else if (bid < 1792) {
        f32x4 z = {0.f, 0.f, 0.f, 0.f};
        float* dst = outz + (size_t)(bid - 1280) * 4096;
        #pragma unroll
        for (int j = 0; j < 4; ++j)
            *(f32x4*)(dst + (size_t)(tid + 256 * j) * 4) = z;
    } else {
        f32x4 z = {0.f, 0.f, 0.f, 0.f};
        float* dst = rsz + (size_t)(bid - 1792) * 4096;
        #pragma unroll
        for (int j = 0; j < 4; ++j)
            *(f32x4*)(dst + (size_t)(tid + 256 * j) * 4) = z;
    }
}

// ---------------- main ----------------
// grid = 1024: blockIdx = mc*16 + nb. Block: rows mc*256..+255, cols nb*256..+255.
// Wave w owns 64 cols (pf loop-invariant, 64 VGPR). X streams through LDS:
// 4 batches x 64 rows, double-buffered, global_load_lds + counted vmcnt(4).
__global__ __launch_bounds__(256, 4) void tide_main(
    const short* __restrict__ Xb, const float* __restrict__ x2g,
    const short* __restrict__ Pb, const float* __restrict__ p2g,
    const float* __restrict__ cg, const float* __restrict__ pcg,
    const short* __restrict__ Vt,
    float* __restrict__ rsum_g, float* __restrict__ oaccum)
{
    __shared__ __attribute__((aligned(16))) short xt[2][64 * DD];     // 32 KB
    __shared__ __attribute__((aligned(16))) float x2t[256];           // 1 KB
    __shared__ __attribute__((aligned(16))) short lds_w[4][16 * 32];  // cold only

    const int tid = threadIdx.x;
    const int wid = tid >> 6, lane = tid & 63;
    const int lo = lane & 15, hi = lane >> 4;
    const int nb = blockIdx.x & 15, mc = blockIdx.x >> 4;
    const int mb = mc * 256;
    const int c0 = nb * 256 + wid * 64;

    // loop-invariant P fragments: lane holds P[n=c0+f*16+lo][k=(kf*4+hi)*8+j]
    short8 pf[4][4];
    float pc[4];
    #pragma unroll
    for (int f = 0; f < 4; ++f) {
        #pragma unroll
        for (int kf = 0; kf < 4; ++kf)
            pf[f][kf] = *(const short8*)(Pb + (size_t)(c0 + f * 16 + lo) * DD
                                            + (kf * 4 + hi) * 8);
        pc[f] = pcg[c0 + f * 16 + lo];
    }

    // staging map: thread stages rows (tid>>4)+16i, 16B chunk (tid&15), with
    // source chunk pre-swizzled by row&15 (== tid>>4 for all i) -> linear dest.
    const int srow = tid >> 4, sch = tid & 15;
    const short* xsrc = Xb + (size_t)(mb + srow) * DD + ((sch ^ srow) * 8);
    short* ldst = (short*)xt + tid * 8;

    // prologue: stage batch 0 into buf 0; x2 chunk -> LDS
    #pragma unroll
    for (int i = 0; i < 4; ++i)
        __builtin_amdgcn_global_load_lds(
            (const __attribute__((address_space(1))) void*)(xsrc + i * 2048),
            (__attribute__((address_space(3))) void*)(ldst + i * 2048), 16, 0, 0);
    x2t[tid] = x2g[mb + tid];
    __syncthreads();   // full vmcnt+lgkm drain: batch 0 staged, x2 ready

    float emin = 3.4e38f;   // min of all e (fminf drops NaNs...)
    float echk = 0.f;       // ...so a sum companion catches them

    #pragma unroll 1
    for (int b = 0; b < 4; ++b) {
        // stage batch b+1 (b=3: dummy re-stage of batch 0, keeps loop uniform)
        const int bs = (b + 1) & 3;
        short* ld1 = ldst + ((b + 1) & 1) * 8192;
        #pragma unroll
        for (int i = 0; i < 4; ++i)
            __builtin_amdgcn_global_load_lds(
                (const __attribute__((address_space(1))) void*)(xsrc + bs * 8192 + i * 2048),
                (__attribute__((address_space(3))) void*)(ld1 + i * 2048), 16, 0, 0);
        asm volatile("s_waitcnt vmcnt(4)" ::: "memory");  // batch b landed
        __builtin_amdgcn_sched_barrier(0);
        __builtin_amdgcn_s_barrier();                     // all waves staged b
        __builtin_amdgcn_sched_barrier(0);

        const short* xb = (const short*)xt + (b & 1) * 8192;
        #pragma unroll
        for (int u = 0; u < 4; ++u) {
            short8 xf[4];
            #pragma unroll
            for (int kf = 0; kf < 4; ++kf) {
                int q = (kf * 4 + hi) ^ lo;   // un-swizzle on read
                xf[kf] = *(const short8*)(xb + (u * 16 + lo) * DD + q * 8);
            }
            f32x4 x2r = *(const f32x4*)(x2t + b * 64 + u * 16 + hi * 4);
            #pragma unroll
            for (int f = 0; f < 4; ++f) {
                f32x4 s = {0.f, 0.f, 0.f, 0.f};
                #pragma unroll
                for (int kf = 0; kf < 4; ++kf)
                    s = __builtin_amdgcn_mfma_f32_16x16x32_bf16(xf[kf], pf[f][kf], s, 0, 0, 0);
                #pragma unroll
                for (int r = 0; r < 4; ++r) {
                    float e = fmaf(s[r], -2.f, x2r[r] + pc[f]);
                    emin = fminf(emin, e);
                    echk += e;
                }
            }
        }
        __builtin_amdgcn_sched_barrier(0);
        __builtin_amdgcn_s_barrier();   // readers of buf b done before overwrite
    }

    const int bad = (!(emin >= 0.f)) | (echk != echk);
    if (__builtin_expect(__any(bad), 0)) {
        // ---- cold exact path: redo this wave's whole tile precisely ----
        const short* xrow = Xb + (size_t)(mb + lo) * DD;
        float p2v[4], cv[4];
        #pragma unroll
        for (int f = 0; f < 4; ++f) {
            p2v[f] = p2g[c0 + f * 16 + lo];
            cv[f]  = cg [c0 + f * 16 + lo];
        }
        #pragma unroll 1
        for (int t = 0; t < 16; ++t) {
            const int m0 = mb + t * 16;
            short8 xf[4];
            #pragma unroll
            for (int kf = 0; kf < 4; ++kf)
                xf[kf] = *(const short8*)(xrow + (size_t)t * 16 * DD + (kf * 4 + hi) * 8);
            f32x4 x2r = *(const f32x4*)(x2g + m0 + hi * 4);
            #pragma unroll
            for (int pr = 0; pr < 2; ++pr) {
                f32x4 s0 = {0.f,0.f,0.f,0.f}, s1 = {0.f,0.f,0.f,0.f};
                #pragma unroll
                for (int kf = 0; kf < 4; ++kf) {
                    s0 = __builtin_amdgcn_mfma_f32_16x16x32_bf16(xf[kf], pf[2*pr][kf],   s0, 0, 0, 0);
                    s1 = __builtin_amdgcn_mfma_f32_16x16x32_bf16(xf[kf], pf[2*pr+1][kf], s1, 0, 0, 0);
                }
                float w[8], wmax = 0.f;
                #pragma unroll
                for (int r = 0; r < 4; ++r) {
                    float d2a = fmaf(s0[r], -2.f, x2r[r] + p2v[2*pr]);
                    float d2b = fmaf(s1[r], -2.f, x2r[r] + p2v[2*pr+1]);
                    d2a = fmaxf(d2a, 0.f); d2b = fmaxf(d2b, 0.f);
                    float wa = exp2f(__builtin_amdgcn_sqrtf(d2a) * cv[2*pr]);
                    float wb = exp2f(__builtin_amdgcn_sqrtf(d2b) * cv[2*pr+1]);
                    w[r] = wa; w[4 + r] = wb;
                    wmax = fmaxf(wmax, fmaxf(wa, wb));
                }
                if (__any(wmax > 0.f)) {
                    #pragma unroll
                    for (int r = 0; r < 4; ++r) {
                        float v = w[r] + w[4 + r];
                        v += __shfl_xor(v, 1); v += __shfl_xor(v, 2);
                        v += __shfl_xor(v, 4); v += __shfl_xor(v, 8);
                        if (lo == 0) atomicAdd(&rsum_g[m0 + hi * 4 + r], v);
                    }
                    #pragma unroll
                    for (int r = 0; r < 4; ++r) {
                        lds_w[wid][(hi * 4 + r) * 32 + lo]      = f2bf(w[r]);
                        lds_w[wid][(hi * 4 + r) * 32 + 16 + lo] = f2bf(w[4 + r]);
                    }
                    short8 wfr = *(const short8*)(&lds_w[wid][lo * 32 + hi * 8]);
                    #pragma unroll
                    for (int df = 0; df < 8; ++df) {
                        short8 vf = *(const short8*)(Vt + (size_t)(df * 16 + lo) * NTOT
                                                        + c0 + pr * 32 + hi * 8);
                        f32x4 of = {0.f,0.f,0.f,0.f};
                        of = __builtin_amdgcn_mfma_f32_16x16x32_bf16(wfr, vf, of, 0, 0, 0);
                        #pragma unroll
                        for (int r = 0; r < 4; ++r)
                            atomicAdd(&oaccum[(size_t)(m0 + hi * 4 + r) * DD + df * 16 + lo],
                                      of[r]);
                    }
                }
            }
        }
    }
}

// ---------------- normalize: only rows with nonzero rsum need work ----------
__global__ __launch_bounds__(256) void tide_norm(
    const float* __restrict__ rsum_g, float* __restrict__ outp)
{
    const int row = blockIdx.x * 256 + threadIdx.x;
    float s = rsum_g[row];
    if (s != 0.f) {
        float inv = 1.f / (s + 1e-8f);
        float* p = outp + (size_t)row * DD;
        #pragma unroll 4
        for (int j = 0; j < DD / 4; ++j) {
            f32x4 v = *(f32x4*)(p + j * 4);
            v[0] *= inv; v[1] *= inv; v[2] *= inv; v[3] *= inv;
            *(f32x4*)(p + j * 4) = v;
        }
    }
    // s == 0: out row already exact (0 / (0 + 1e-8) = 0, pre-zeroed)
}

extern "C" void kernel_launch(void* const* d_in, const int* in_sizes, int n_in,
                              void* d_out, int out_size, void* d_ws, size_t ws_size,
                              hipStream_t stream) {
    const float* x    = (const float*)d_in[0];  // [8,2048,128]
    const float* pos  = (const float*)d_in[1];  // [4096,128]
    const float* val  = (const float*)d_in[2];  // [4096,128]
    const float* temp = (const float*)d_in[3];  // [4096]
    float* out = (float*)d_out;

    char* ws = (char*)d_ws;
    short* Xb     = (short*)(ws);                    // 4 MB
    short* Pb     = (short*)(ws + 4194304);          // 1 MB
    short* Vt     = (short*)(ws + 5242880);          // 1 MB
    float* x2g    = (float*)(ws + 6291456);          // 64 KB
    float* p2g    = (float*)(ws + 6356992);          // 16 KB
    float* cg     = (float*)(ws + 6373376);          // 16 KB
    float* pcg    = (float*)(ws + 6389760);          // 16 KB
    float* rsum_g = (float*)(ws + 6406144);          // 64 KB

    hipLaunchKernelGGL(tide_prep, dim3(1796), dim3(256), 0, stream,
                       x, pos, val, temp, Xb, x2g, Pb, p2g, cg, pcg, Vt, out, rsum_g);
    hipLaunchKernelGGL(tide_main, dim3(1024), dim3(256), 0, stream,
                       Xb, x2g, Pb, p2g, cg, pcg, Vt, rsum_g, out);
    hipLaunchKernelGGL(tide_norm, dim3(64), dim3(256), 0, stream,
                       rsum_g, out);
}